// Round 11
// baseline (497.209 us; speedup 1.0000x reference)
//
#include <hip/hip_runtime.h>

typedef _Float16 half8 __attribute__((ext_vector_type(8)));
typedef _Float16 half4v __attribute__((ext_vector_type(4)));
typedef float floatx4 __attribute__((ext_vector_type(4)));

#define LBF 2304   // Lb == Lf
#define K1  1152
#define LDK2 2304  // worst-case compacted stride (Kc can be up to 2304)

__device__ __forceinline__ void gll16(const _Float16* g, _Float16* l) {
    __builtin_amdgcn_global_load_lds((const __attribute__((address_space(1))) void*)g,
                                     (__attribute__((address_space(3))) void*)l, 16, 0, 0);
}

// decode Kc from signed pos'[2303] (excl-scan encoding: valid->e, masked->-e-1)
__device__ __forceinline__ int dec_kc(int s) { return (s >= 0) ? s + 1 : -s - 1; }

// ---------------- mask scan (single block): mask -> signed compaction pos' ----
__global__ __launch_bounds__(256)
void mask_scan(const float* __restrict__ mask, int* __restrict__ pos) {
    __shared__ float msk[48 * 48];
    int tid = threadIdx.x;
    for (int i = tid; i < 2304; i += 256) {
        int y = i / 48, x = i % 48;
        msk[i] = mask[(8 * y) * 384 + 8 * x];
    }
    __syncthreads();
    int mmb[9], loc[9]; int s = 0;
#pragma unroll
    for (int t = 0; t < 9; t++) {
        int p = tid * 9 + t;
        int pi = p / 48, pj = p % 48;
        float sm = 0.f;
#pragma unroll
        for (int u = 0; u < 3; u++)
#pragma unroll
            for (int v = 0; v < 3; v++) {
                int y = pi - 1 + u, x = pj - 1 + v;
                if ((unsigned)y < 48u && (unsigned)x < 48u)
                    sm += msk[y * 48 + x];
            }
        int m = (sm == 0.f) ? 1 : 0;
        mmb[t] = m; loc[t] = s; s += m;
    }
    __shared__ int sh[256];
    sh[tid] = s; __syncthreads();
    for (int off = 1; off < 256; off <<= 1) {
        int v = (tid >= off) ? sh[tid - off] : 0;
        __syncthreads();
        sh[tid] += v;
        __syncthreads();
    }
    int excl = sh[tid] - s;
#pragma unroll
    for (int t = 0; t < 9; t++) {
        int e = excl + loc[t];
        pos[tid * 9 + t] = mmb[t] ? e : (-e - 1);
    }
}

// ---------------- prep: fp (z=0) and wn (z=1) rows, direct from f / bsrc ------
// R11: 8B half4 stores (coalesced) instead of 2B scalar stores.
__global__ __launch_bounds__(256)
void prep_fw(const float* __restrict__ f, const float* __restrict__ bsrc,
             _Float16* __restrict__ fp, _Float16* __restrict__ wn) {
    int p = blockIdx.x, b = blockIdx.y;
    int pi = p / 48, pj = p % 48, tid = threadIdx.x;
    if (blockIdx.z == 0) {
        const float* fb = f + (long)b * 128 * 96 * 96;
        _Float16* orow = fp + ((long)b * LBF + p) * K1;
#pragma unroll
        for (int i = 0; i < 2; i++) {
            int qi = tid + i * 256;
            if (qi < 288) {
                int k0 = qi * 4;
                half4v o;
#pragma unroll
                for (int e = 0; e < 4; e++) {
                    int k = k0 + e;
                    int c = k / 9, r = k - 9 * c, u = r / 3, v = r - 3 * u;
                    int y = pi - 1 + u, x = pj - 1 + v;
                    float val = 0.f;
                    if ((unsigned)y < 48u && (unsigned)x < 48u)
                        val = fb[(c * 96 + 2 * y) * 96 + 2 * x];
                    o[e] = (_Float16)val;
                }
                *(half4v*)(orow + k0) = o;
            }
        }
    } else {
        const float* bb = bsrc + (long)b * 128 * 96 * 96;
        _Float16* orow = wn + ((long)b * LBF + p) * K1;
        float w[2][4]; float ss = 0.f;
#pragma unroll
        for (int i = 0; i < 2; i++) {
            int qi = tid + i * 256;
#pragma unroll
            for (int e = 0; e < 4; e++) {
                float val = 0.f;
                if (qi < 288) {
                    int k = qi * 4 + e;
                    int c = k / 9, r = k - 9 * c, u = r / 3, v = r - 3 * u;
                    int y = pi - 1 + u, x = pj - 1 + v;
                    if ((unsigned)y < 48u && (unsigned)x < 48u)
                        val = bb[(c * 96 + 2 * y) * 96 + 2 * x];
                }
                w[i][e] = val; ss += val * val;
            }
        }
        for (int m = 32; m; m >>= 1) ss += __shfl_xor(ss, m);
        __shared__ float sh[4];
        if ((tid & 63) == 0) sh[tid >> 6] = ss;
        __syncthreads();
        float denom = sqrtf(sh[0] + sh[1] + sh[2] + sh[3] + 0.1152f);
        float inv = 1.f / denom;
#pragma unroll
        for (int i = 0; i < 2; i++) {
            int qi = tid + i * 256;
            if (qi < 288) {
                half4v o;
#pragma unroll
                for (int e = 0; e < 4; e++) o[e] = (_Float16)(w[i][e] * inv);
                *(half4v*)(orow + qi * 4) = o;
            }
        }
    }
}

// ---------------- prep: compacted Wt, line-efficient ---------------------------
__global__ void prep_wtc(const float* __restrict__ bsrc, const int* __restrict__ pos,
                         _Float16* __restrict__ wtc) {
    int p = blockIdx.x * 256 + threadIdx.x;   // [0,2304)
    int c = blockIdx.y;                       // [0,128)
    int b = blockIdx.z;
    int sp = pos[p];
    long base = ((long)b * 2048 + c * 16) * LDK2;
    if (sp < 0) {
        int kc = dec_kc(pos[2303]);
        int kp = (kc + 63) & ~63;
        int mo = p + sp + 1;                  // masked ordinal
        if (mo < kp - kc) {
#pragma unroll
            for (int n = 0; n < 16; n++)
                wtc[base + (long)n * LDK2 + kc + mo] = (_Float16)0.f;
        }
        return;
    }
    int pi = p / 48, pj = p % 48;
    const float* src = bsrc + ((long)b * 128 + c) * 96 * 96;
#pragma unroll
    for (int u = 0; u < 4; u++) {
        int y = 2 * pi - 1 + u;
        bool yok = (unsigned)y < 96u;
#pragma unroll
        for (int v = 0; v < 4; v++) {
            int x = 2 * pj - 1 + v;
            float val = 0.f;
            if (yok && (unsigned)x < 96u) val = src[y * 96 + x];
            wtc[base + (long)(u * 4 + v) * LDK2 + sp] = (_Float16)val;
        }
    }
}

// ======================= GEMM1: 128x128 tile, 4 waves, counted-vmcnt ==========
// R11: z-split (2 batches per dispatch) for top-5 visibility; structure frozen
// (four sync variants measured 75-79 us — schedule is not the limiter here).
#define G1_REG 4096   // 128 * 32 halves (8 KB) per region

__global__ __launch_bounds__(256)
void gemm1_cv(const _Float16* __restrict__ A, const _Float16* __restrict__ B,
              float* __restrict__ C, int zoff) {
    __shared__ _Float16 SA[4 * G1_REG];
    __shared__ _Float16 SB[4 * G1_REG];

    // 648 blocks = 2 batches * 18 * 18; bijective XCD swizzle (648 % 8 == 0)
    int bid = blockIdx.x;
    int wg = (bid & 7) * 81 + (bid >> 3);
    int z = zoff + wg / 324; int t = wg % 324;
    const int m0 = (t / 18) * 128, n0 = (t % 18) * 128;

    const _Float16* gA = A + (long)z * LBF * K1 + (long)m0 * K1;
    const _Float16* gB = B + (long)z * LBF * K1 + (long)n0 * K1;
    float* Cb = C + (long)z * LBF * LBF;

    const int tid = threadIdx.x;
    const int wave = tid >> 6, lane = tid & 63;
    const int lm = lane & 15, q = lane >> 4;
    const int wm = wave >> 1, wn_ = wave & 1;
    const int soff = (q ^ ((lm >> 1) & 3)) * 8;
    const int srow = lane >> 2;                               // row in 16-row chunk
    const int scol = ((lane & 3) ^ ((lane >> 3) & 3)) * 8;    // swizzled k-halves

    floatx4 acc[4][4] = {};

    auto stA = [&](int reg, int kcol) {  // 8 KB region: 2 glls/thread
        _Float16* dst = SA + reg * G1_REG + wave * 1024;
        gll16(gA + (long)(wave * 32 + srow) * K1 + kcol + scol, dst);
        gll16(gA + (long)(wave * 32 + 16 + srow) * K1 + kcol + scol, dst + 512);
    };
    auto stB = [&](int reg, int kcol) {
        _Float16* dst = SB + reg * G1_REG + wave * 1024;
        gll16(gB + (long)(wave * 32 + srow) * K1 + kcol + scol, dst);
        gll16(gB + (long)(wave * 32 + 16 + srow) * K1 + kcol + scol, dst + 512);
    };
    auto ldA = [&](int reg, int i) -> half8 {
        return *(const half8*)&SA[reg * G1_REG + (wm * 64 + i * 16 + lm) * 32 + soff];
    };
    auto ldB = [&](int reg, int j) -> half8 {
        return *(const half8*)&SB[reg * G1_REG + (wn_ * 64 + j * 16 + lm) * 32 + soff];
    };

    // prologue: [0][0]<-t0ks0, [0][1]<-t0ks1, [1][0]<-t1ks0  (12 glls/thread)
    stA(0, 0);  stB(0, 0);
    stA(1, 32); stB(1, 32);
    stA(2, 64); stB(2, 64);
    asm volatile("s_waitcnt vmcnt(8)" ::: "memory");  // oldest batch (t0ks0) landed
    __builtin_amdgcn_s_barrier();
    __builtin_amdgcn_sched_barrier(0);

    for (int k = 0; k < 18; ++k) {
        const int b = k & 1;
        const int rg0 = b * 2, rg1 = rg0 + 1, og1 = (b ^ 1) * 2 + 1;
        // ---------- phase q0: compute ks0 ----------
        {
            half8 af[4], bf[4];
#pragma unroll
            for (int i = 0; i < 4; ++i) af[i] = ldA(rg0, i);
#pragma unroll
            for (int j = 0; j < 4; ++j) bf[j] = ldB(rg0, j);
            if (k + 1 < 18) {
                int kc = (k + 1) * 64 + 32;
                stA(og1, kc); stB(og1, kc);
                asm volatile("s_waitcnt vmcnt(8) lgkmcnt(0)" ::: "memory");
            } else {
                asm volatile("s_waitcnt vmcnt(0) lgkmcnt(0)" ::: "memory");
            }
            __builtin_amdgcn_s_barrier();
            __builtin_amdgcn_sched_barrier(0);
            __builtin_amdgcn_s_setprio(1);
#pragma unroll
            for (int i = 0; i < 4; ++i)
#pragma unroll
                for (int j = 0; j < 4; ++j)
                    acc[i][j] = __builtin_amdgcn_mfma_f32_16x16x32_f16(af[i], bf[j], acc[i][j], 0, 0, 0);
            __builtin_amdgcn_s_setprio(0);
        }
        // ---------- phase q1: compute ks1 ----------
        {
            half8 af[4], bf[4];
#pragma unroll
            for (int i = 0; i < 4; ++i) af[i] = ldA(rg1, i);
#pragma unroll
            for (int j = 0; j < 4; ++j) bf[j] = ldB(rg1, j);
            if (k + 2 < 18) {
                int kc = (k + 2) * 64;
                stA(rg0, kc); stB(rg0, kc);
                asm volatile("s_waitcnt vmcnt(8) lgkmcnt(0)" ::: "memory");
            } else {
                asm volatile("s_waitcnt vmcnt(0) lgkmcnt(0)" ::: "memory");
            }
            __builtin_amdgcn_s_barrier();
            __builtin_amdgcn_sched_barrier(0);
            __builtin_amdgcn_s_setprio(1);
#pragma unroll
            for (int i = 0; i < 4; ++i)
#pragma unroll
                for (int j = 0; j < 4; ++j)
                    acc[i][j] = __builtin_amdgcn_mfma_f32_16x16x32_f16(af[i], bf[j], acc[i][j], 0, 0, 0);
            __builtin_amdgcn_s_setprio(0);
        }
    }

    // C/D layout: col = lane&15, row = (lane>>4)*4 + reg   [m89-verified]
    const int col = n0 + wn_ * 64 + lm;
#pragma unroll
    for (int i = 0; i < 4; ++i) {
        const int row = m0 + wm * 64 + i * 16 + q * 4;
#pragma unroll
        for (int j = 0; j < 4; ++j)
#pragma unroll
            for (int r = 0; r < 4; ++r)
                Cb[(long)(row + r) * LBF + col + j * 16] = acc[i][j][r];
    }
}

// ---------------- NT GEMM, BK=64, double-buffered LDS (R6 winner) — GEMM2 -----
__device__ __forceinline__ void gemm_compute(const _Float16* lA, const _Float16* lB,
                                             floatx4 (&acc)[4][4],
                                             int wr, int wc, int lm, int pcp) {
    half8 af[4], bf[4];
#pragma unroll
    for (int t = 0; t < 4; t++) {
        af[t] = *(const half8*)&lA[(wr * 64 + t * 16 + lm) * 64 + pcp];
        bf[t] = *(const half8*)&lB[(wc * 64 + t * 16 + lm) * 64 + pcp];
    }
#pragma unroll
    for (int i = 0; i < 4; i++)
#pragma unroll
        for (int j = 0; j < 4; j++)
            acc[i][j] = __builtin_amdgcn_mfma_f32_16x16x32_f16(af[i], bf[j], acc[i][j], 0, 0, 0);
#pragma unroll
    for (int t = 0; t < 4; t++) {
        af[t] = *(const half8*)&lA[(wr * 64 + t * 16 + lm) * 64 + (pcp ^ 32)];
        bf[t] = *(const half8*)&lB[(wc * 64 + t * 16 + lm) * 64 + (pcp ^ 32)];
    }
#pragma unroll
    for (int i = 0; i < 4; i++)
#pragma unroll
        for (int j = 0; j < 4; j++)
            acc[i][j] = __builtin_amdgcn_mfma_f32_16x16x32_f16(af[i], bf[j], acc[i][j], 0, 0, 0);
}

__global__ __launch_bounds__(256)
void gemm_nt64(const _Float16* __restrict__ A, const _Float16* __restrict__ B,
               float* __restrict__ C, int M, int N, int ldk, int swapxy,
               const int* __restrict__ Kpos, int Kstat, long sA, long sB, long sC,
               int zoff) {
    int zz = blockIdx.z + zoff;
    A += zz * sA; B += zz * sB; C += zz * sC;
    int K;
    if (Kpos) { int kc = dec_kc(Kpos[0]); K = (kc + 63) & ~63; }
    else K = Kstat;
    const int tid = threadIdx.x;
    const int lane = tid & 63, wave = tid >> 6;
    const int wr = wave >> 1, wc = wave & 1;
    const int bm = swapxy ? blockIdx.x : blockIdx.y;
    const int bn = swapxy ? blockIdx.y : blockIdx.x;
    const int m0 = bm * 128, n0 = bn * 128;

    __shared__ _Float16 sm[4][128 * 64];   // [buf*2 + (A=0/B=1)]: 4 x 16 KB

    floatx4 acc[4][4] = {};

    const int lm = lane & 15, q = lane >> 4;
    const int pcp = (q ^ (lm & 7)) * 8;      // substep-0 phys offset (halves)

    const int srow8 = lane >> 3;
    const int gc = ((lane & 7) ^ srow8) * 8;  // global halves offset (XOR swizzle)
    const _Float16* gA[4]; const _Float16* gB[4];
    int dOff[4];
#pragma unroll
    for (int c = 0; c < 4; c++) {
        int r = (wave * 4 + c) * 8 + srow8;
        gA[c] = A + (long)(m0 + r) * ldk + gc;
        gB[c] = B + (long)(n0 + r) * ldk + gc;
        dOff[c] = (wave * 4 + c) * 512;
    }

    if (K > 0) {
#pragma unroll
        for (int c = 0; c < 4; c++) gll16(gA[c], &sm[0][dOff[c]]);
#pragma unroll
        for (int c = 0; c < 4; c++) gll16(gB[c], &sm[1][dOff[c]]);
        __syncthreads();
        int k0 = 0, buf = 0;
        while (true) {
            int kn = k0 + 64;
            if (kn < K) {
                const int nb = (buf ^ 1) * 2;
#pragma unroll
                for (int c = 0; c < 4; c++) gll16(gA[c] + kn, &sm[nb][dOff[c]]);
#pragma unroll
                for (int c = 0; c < 4; c++) gll16(gB[c] + kn, &sm[nb + 1][dOff[c]]);
            }
            gemm_compute(sm[buf * 2], sm[buf * 2 + 1], acc, wr, wc, lm, pcp);
            __syncthreads();
            k0 = kn; buf ^= 1;
            if (k0 >= K) break;
        }
    }

    // C/D layout: col = lane&15, row = (lane>>4)*4 + reg   [m89-verified]
    const int col = n0 + wc * 64 + lm;
    const int rowq = q * 4;
#pragma unroll
    for (int i = 0; i < 4; i++) {
        int row = m0 + wr * 64 + i * 16 + rowq;
#pragma unroll
        for (int j = 0; j < 4; j++)
#pragma unroll
            for (int r = 0; r < 4; r++)
                C[(long)(row + r) * N + col + j * 16] = acc[i][j][r];
    }
}

// ---------------- fuse pass A: 2 rows/block, float4, register reuse -----------
// out[y][x] = S[y][x] + (y>0)*S[y-1][x-1] + (y<LBF-1)*S[y+1][x+1]  (bounded x)
__global__ __launch_bounds__(256)
void fuseA(const float* __restrict__ ST, float* __restrict__ FT1) {
    int y0 = blockIdx.x * 2, bb = blockIdx.y;
    const float* S = ST + (long)bb * LBF * LBF;
    float* F = FT1 + (long)bb * LBF * LBF;
    const float* rm1 = S + (long)(y0 > 0 ? y0 - 1 : 0) * LBF;
    const float* r0  = S + (long)y0 * LBF;
    const float* r1  = S + (long)(y0 + 1) * LBF;                       // y0+1 <= 2303
    const float* r2  = S + (long)(y0 + 2 < LBF ? y0 + 2 : y0 + 1) * LBF;
    float mA = (y0 > 0) ? 1.f : 0.f;          // out0 upper tap valid
    float mB = (y0 + 2 < LBF) ? 1.f : 0.f;    // out1 lower tap valid
    float* o0 = F + (long)y0 * LBF;
    float* o1 = F + (long)(y0 + 1) * LBF;
    int tid = threadIdx.x;
#pragma unroll
    for (int u = 0; u < 3; u++) {
        int qq = tid + u * 256;              // float4 index [0, 576)
        if (qq < LBF / 4) {
            int x0 = qq * 4;
            float4 vm1 = *(const float4*)(rm1 + x0);
            float4 v0  = *(const float4*)(r0 + x0);
            float4 v1  = *(const float4*)(r1 + x0);
            float4 v2  = *(const float4*)(r2 + x0);
            float lo0 = (x0 > 0) ? rm1[x0 - 1] : 0.f;
            float lo1 = (x0 > 0) ? r0[x0 - 1] : 0.f;
            float hi0 = (x0 + 4 < LBF) ? r1[x0 + 4] : 0.f;
            float hi1 = (x0 + 4 < LBF) ? r2[x0 + 4] : 0.f;
            float4 out0, out1;
            out0.x = v0.x + mA * lo0   + v1.y;   // row y0: lower tap always valid
            out0.y = v0.y + mA * vm1.x + v1.z;
            out0.z = v0.z + mA * vm1.y + v1.w;
            out0.w = v0.w + mA * vm1.z + hi0;
            out1.x = v1.x + lo1  + mB * v2.y;    // row y0+1: upper tap always valid
            out1.y = v1.y + v0.x + mB * v2.z;
            out1.z = v1.z + v0.y + mB * v2.w;
            out1.w = v1.w + v0.z + mB * hi1;
            *(float4*)(o0 + x0) = out0;
            *(float4*)(o1 + x0) = out1;
        }
    }
}

// ---------------- fuse pass B + masked softmax + compaction + self-pad --------
__global__ __launch_bounds__(256)
void fuseB_softmax(const float* __restrict__ FT1, const int* __restrict__ pos,
                   _Float16* __restrict__ attTc_g) {
    int j = blockIdx.x, bb = blockIdx.y;
    int tid = threadIdx.x;
    const float* F = FT1 + (long)bb * LBF * LBF;
    _Float16* orow = attTc_g + ((long)bb * LBF + j) * LDK2;
    int Pj = (j % 48) * 48 + j / 48;
    long roff[3]; bool jok[3];
#pragma unroll
    for (int t = 0; t < 3; t++) {
        int j2 = Pj + t - 1;
        jok[t] = (unsigned)j2 < (unsigned)LBF;
        int jc = jok[t] ? j2 : 0;
        roff[t] = (long)((jc % 48) * 48 + jc / 48) * LBF;
    }
    float v[9]; int ps[9];
    float mx = -1e30f;
#pragma unroll
    for (int u = 0; u < 9; u++) {
        int x = tid + u * 256;
        int sp = pos[x];
        ps[u] = sp;
        float xv = 0.f;
        if (sp >= 0) {
            int a = x / 48, b = x - a * 48;
            int Px = b * 48 + a;
            float acc = 0.f;
#pragma unroll
            for (int t = 0; t < 3; t++) {
                int d2 = t - 1;
                int uu = Px + d2;
                if (jok[t] && (unsigned)uu < (unsigned)LBF) {
                    int ad = a + d2;
                    int c = ((unsigned)ad < 48u) ? (x + 48 * d2)
                          : (ad == 48 ? (b + 1) : (2255 + b));
                    acc += F[roff[t] + c];
                }
            }
            xv = acc * 10.f;
        }
        v[u] = xv;
        mx = fmaxf(mx, xv);
    }
    for (int m = 32; m; m >>= 1) mx = fmaxf(mx, __shfl_xor(mx, m));
    __shared__ float sh[4], sh2[4];
    if ((tid & 63) == 0) sh[tid >> 6] = mx;
    __syncthreads();
    mx = fmaxf(fmaxf(sh[0], sh[1]), fmaxf(sh[2], sh[3]));
    float sum = 0.f;
#pragma unroll
    for (int u = 0; u < 9; u++) { v[u] = __expf(v[u] - mx); sum += v[u]; }
    for (int m = 32; m; m >>= 1) sum += __shfl_xor(sum, m);
    if ((tid & 63) == 0) sh2[tid >> 6] = sum;
    __syncthreads();
    sum = sh2[0] + sh2[1] + sh2[2] + sh2[3];
    float inv = 1.f / sum;
#pragma unroll
    for (int u = 0; u < 9; u++) {
        if (ps[u] >= 0) orow[ps[u]] = (_Float16)(v[u] * inv);
    }
    int kc = dec_kc(pos[2303]);
    int kp = (kc + 63) & ~63;
    if (tid < kp - kc) orow[kc + tid] = (_Float16)0.f;
}

// ---------------- scatter from MT[n][p]: coalesced transposed-conv gather -----
__global__ void scatter_out(const float* __restrict__ MT_, float* __restrict__ out) {
    int yx = blockIdx.x * 256 + threadIdx.x;  // [0, 9216)
    int c = blockIdx.y, b = blockIdx.z;
    int y = yx / 96, x = yx % 96;
    const float* Mb = MT_ + (long)b * 2048 * LBF;
    float s = 0.f;
    for (int uu = (y + 1) & 1; uu < 4; uu += 2) {
        int fi = (y + 1 - uu) >> 1;
        if ((unsigned)fi >= 48u) continue;
        for (int vv = (x + 1) & 1; vv < 4; vv += 2) {
            int fj = (x + 1 - vv) >> 1;
            if ((unsigned)fj >= 48u) continue;
            s += Mb[(long)(c * 16 + uu * 4 + vv) * LBF + fi * 48 + fj];
        }
    }
    out[(((long)b * 128 + c) * 96 + y) * 96 + x] = 0.25f * s;
}

extern "C" void kernel_launch(void* const* d_in, const int* in_sizes, int n_in,
                              void* d_out, int out_size, void* d_ws, size_t ws_size,
                              hipStream_t stream) {
    const float* f    = (const float*)d_in[0];
    const float* bsrc = (const float*)d_in[1];
    const float* mask = (const float*)d_in[2];
    float* out = (float*)d_out;

    char* ws = (char*)d_ws;
    const size_t offR1  = 84934656;
    const size_t offWn  = offR1 + 21233664;
    const size_t offWtc = offR1 + 42467328;
    const size_t offFT1 = offWtc + 37748736;          // 165150720
    const size_t offPos = offFT1 + 2ul * 21233664;    // 207618048
    const size_t NEED   = offPos + 9216;              // 207627264
    if (ws_size < NEED) return;  // visible failure, no OOB writes

    float*    ST    = (float*)(ws + 0);
    float*    MT    = (float*)(ws + 0);
    _Float16* fp    = (_Float16*)(ws + offR1);
    _Float16* wn    = (_Float16*)(ws + offWn);
    _Float16* attTc = (_Float16*)(ws + offR1);
    _Float16* Wtc   = (_Float16*)(ws + offWtc);
    float*    FT1   = (float*)(ws + offFT1);   // 2-batch FT1 slot
    int*      pos   = (int*)(ws + offPos);

    mask_scan<<<dim3(1), 256, 0, stream>>>(mask, pos);
    prep_fw<<<dim3(2304, 4, 2), 256, 0, stream>>>(f, bsrc, fp, wn);
    prep_wtc<<<dim3(9, 128, 4), 256, 0, stream>>>(bsrc, pos, Wtc);

    // GEMM1: ST[j,i] = sum_k fp[j,k] * wn[i,k]  (static K=1152); z-split halves
    gemm1_cv<<<dim3(648), 256, 0, stream>>>(fp, wn, ST, 0);
    gemm1_cv<<<dim3(648), 256, 0, stream>>>(fp, wn, ST, 2);

    // proven fuse split: streaming fuseA (2-row float4) + fuseB softmax
    for (int g = 0; g < 2; g++) {
        fuseA<<<dim3(LBF / 2, 2), 256, 0, stream>>>(ST + (long)g * 2 * LBF * LBF, FT1);
        fuseB_softmax<<<dim3(LBF, 2), 256, 0, stream>>>(FT1, pos,
            attTc + (long)g * 2 * LBF * LDK2);
    }

    // GEMM2 transposed output, R4 block-order: x sweeps Wtc (A), y pins attTc (B)
    gemm_nt64<<<dim3(16, 18, 2), 256, 0, stream>>>(Wtc, attTc, MT, 2048, 2304, LDK2, 1,
        pos + 2303, 0, (long)2048 * LDK2, (long)2304 * LDK2, (long)2048 * 2304, 0);
    gemm_nt64<<<dim3(16, 18, 2), 256, 0, stream>>>(Wtc, attTc, MT, 2048, 2304, LDK2, 1,
        pos + 2303, 0, (long)2048 * LDK2, (long)2304 * LDK2, (long)2048 * 2304, 2);

    scatter_out<<<dim3(36, 128, 4), 256, 0, stream>>>(MT, out);
}

// Round 12
// 437.418 us; speedup vs baseline: 1.1367x; 1.1367x over previous
//
#include <hip/hip_runtime.h>

typedef _Float16 half8 __attribute__((ext_vector_type(8)));
typedef float floatx4 __attribute__((ext_vector_type(4)));

#define LBF 2304   // Lb == Lf
#define K1  1152
#define LDK2 2304  // worst-case compacted stride (Kc can be up to 2304)

__device__ __forceinline__ void gll16(const _Float16* g, _Float16* l) {
    __builtin_amdgcn_global_load_lds((const __attribute__((address_space(1))) void*)g,
                                     (__attribute__((address_space(3))) void*)l, 16, 0, 0);
}

// decode Kc from signed pos'[2303] (excl-scan encoding: valid->e, masked->-e-1)
__device__ __forceinline__ int dec_kc(int s) { return (s >= 0) ? s + 1 : -s - 1; }

// ---------------- mask scan (single block): mask -> signed compaction pos' ----
__global__ __launch_bounds__(256)
void mask_scan(const float* __restrict__ mask, int* __restrict__ pos) {
    __shared__ float msk[48 * 48];
    int tid = threadIdx.x;
    for (int i = tid; i < 2304; i += 256) {
        int y = i / 48, x = i % 48;
        msk[i] = mask[(8 * y) * 384 + 8 * x];
    }
    __syncthreads();
    int mmb[9], loc[9]; int s = 0;
#pragma unroll
    for (int t = 0; t < 9; t++) {
        int p = tid * 9 + t;
        int pi = p / 48, pj = p % 48;
        float sm = 0.f;
#pragma unroll
        for (int u = 0; u < 3; u++)
#pragma unroll
            for (int v = 0; v < 3; v++) {
                int y = pi - 1 + u, x = pj - 1 + v;
                if ((unsigned)y < 48u && (unsigned)x < 48u)
                    sm += msk[y * 48 + x];
            }
        int m = (sm == 0.f) ? 1 : 0;
        mmb[t] = m; loc[t] = s; s += m;
    }
    __shared__ int sh[256];
    sh[tid] = s; __syncthreads();
    for (int off = 1; off < 256; off <<= 1) {
        int v = (tid >= off) ? sh[tid - off] : 0;
        __syncthreads();
        sh[tid] += v;
        __syncthreads();
    }
    int excl = sh[tid] - s;
#pragma unroll
    for (int t = 0; t < 9; t++) {
        int e = excl + loc[t];
        pos[tid * 9 + t] = mmb[t] ? e : (-e - 1);
    }
}

// ---------------- prep: fp via LDS-staged transpose (R12) ---------------------
// Old gather read 64-way-scattered per VMEM op (73.7 MB fetch, latency-bound).
// Here: block (pi, cg=c/32, b) stages the 3 needed subsampled rows of 32
// channels COALESCED into LDS (reads sweep consecutive x of one channel row),
// then emits the 48x288 output slab with contiguous wave writes.
__global__ __launch_bounds__(256)
void prep_fp2(const float* __restrict__ f, _Float16* __restrict__ fp) {
    int pi = blockIdx.x, cg = blockIdx.y, b = blockIdx.z;
    __shared__ float S[32][3][48];   // [cl][u][x] subsampled taps (18.4 KB)
    int tid = threadIdx.x;
    const float* fb = f + ((long)b * 128 + cg * 32) * 96 * 96;
#pragma unroll
    for (int it = 0; it < 18; ++it) {               // 96 rows x 48 cols = 4608
        int j = tid + it * 256;
        int rowid = j / 48, xx = j - rowid * 48;
        int cl = rowid / 3, u = rowid - 3 * cl;
        int yy = pi - 1 + u;
        float val = 0.f;
        if ((unsigned)yy < 48u)
            val = fb[((long)cl * 96 + 2 * yy) * 96 + 2 * xx];
        S[cl][u][xx] = val;
    }
    __syncthreads();
    _Float16* obase = fp + ((long)b * LBF + (long)pi * 48) * K1 + cg * 288;
#pragma unroll
    for (int it = 0; it < 54; ++it) {               // 48 pj x 288 kk = 13824
        int i = tid + it * 256;
        int pj = i / 288, kk = i - pj * 288;
        int cl = kk / 9, r = kk - 9 * cl, u = r / 3, v = r - 3 * u;
        int x = pj - 1 + v;
        float val = ((unsigned)x < 48u) ? S[cl][u][x] : 0.f;
        obase[(long)pj * K1 + kk] = (_Float16)val;
    }
}

// ---------------- prep: wn rows (R9-proven gather + reduction) ----------------
__global__ __launch_bounds__(256)
void prep_wn(const float* __restrict__ bsrc, _Float16* __restrict__ wn) {
    int p = blockIdx.x, b = blockIdx.y;
    int pi = p / 48, pj = p % 48, tid = threadIdx.x;
    const float* bb = bsrc + (long)b * 128 * 96 * 96;
    _Float16* orow = wn + ((long)b * LBF + p) * K1;
    float w[5]; float ss = 0.f;
#pragma unroll
    for (int i = 0; i < 5; i++) {
        int k = tid + i * 256;
        float val = 0.f;
        if (k < K1) {
            int c = k / 9, r = k - 9 * c, u = r / 3, v = r - 3 * u;
            int y = pi - 1 + u, x = pj - 1 + v;
            if ((unsigned)y < 48u && (unsigned)x < 48u)
                val = bb[(c * 96 + 2 * y) * 96 + 2 * x];
        }
        w[i] = val; ss += val * val;
    }
    for (int m = 32; m; m >>= 1) ss += __shfl_xor(ss, m);
    __shared__ float sh[4];
    if ((tid & 63) == 0) sh[tid >> 6] = ss;
    __syncthreads();
    float denom = sqrtf(sh[0] + sh[1] + sh[2] + sh[3] + 0.1152f);
    float inv = 1.f / denom;
#pragma unroll
    for (int i = 0; i < 5; i++) {
        int k = tid + i * 256;
        if (k < K1) orow[k] = (_Float16)(w[i] * inv);
    }
}

// ---------------- prep: compacted Wt, line-efficient ---------------------------
__global__ void prep_wtc(const float* __restrict__ bsrc, const int* __restrict__ pos,
                         _Float16* __restrict__ wtc) {
    int p = blockIdx.x * 256 + threadIdx.x;   // [0,2304)
    int c = blockIdx.y;                       // [0,128)
    int b = blockIdx.z;
    int sp = pos[p];
    long base = ((long)b * 2048 + c * 16) * LDK2;
    if (sp < 0) {
        int kc = dec_kc(pos[2303]);
        int kp = (kc + 63) & ~63;
        int mo = p + sp + 1;                  // masked ordinal
        if (mo < kp - kc) {
#pragma unroll
            for (int n = 0; n < 16; n++)
                wtc[base + (long)n * LDK2 + kc + mo] = (_Float16)0.f;
        }
        return;
    }
    int pi = p / 48, pj = p % 48;
    const float* src = bsrc + ((long)b * 128 + c) * 96 * 96;
#pragma unroll
    for (int u = 0; u < 4; u++) {
        int y = 2 * pi - 1 + u;
        bool yok = (unsigned)y < 96u;
#pragma unroll
        for (int v = 0; v < 4; v++) {
            int x = 2 * pj - 1 + v;
            float val = 0.f;
            if (yok && (unsigned)x < 96u) val = src[y * 96 + x];
            wtc[base + (long)(u * 4 + v) * LDK2 + sp] = (_Float16)val;
        }
    }
}

// ======================= GEMM1: 128x128 tile, 4 waves, counted-vmcnt ==========
// Structure frozen (four sync variants measured 75-79 us). R10 single-barrier.
#define G1_REG 4096   // 128 * 32 halves (8 KB) per region

__global__ __launch_bounds__(256)
void gemm1_cv(const _Float16* __restrict__ A, const _Float16* __restrict__ B,
              float* __restrict__ C) {
    __shared__ _Float16 SA[4 * G1_REG];
    __shared__ _Float16 SB[4 * G1_REG];

    // 1296 blocks = 4 batch * 18 * 18; bijective XCD swizzle (1296 % 8 == 0)
    int bid = blockIdx.x;
    int wg = (bid & 7) * 162 + (bid >> 3);
    int z = wg / 324; int t = wg - z * 324;
    const int m0 = (t / 18) * 128, n0 = (t % 18) * 128;

    const _Float16* gA = A + (long)z * LBF * K1 + (long)m0 * K1;
    const _Float16* gB = B + (long)z * LBF * K1 + (long)n0 * K1;
    float* Cb = C + (long)z * LBF * LBF;

    const int tid = threadIdx.x;
    const int wave = tid >> 6, lane = tid & 63;
    const int lm = lane & 15, q = lane >> 4;
    const int wm = wave >> 1, wn_ = wave & 1;
    const int soff = (q ^ ((lm >> 1) & 3)) * 8;
    const int srow = lane >> 2;                               // row in 16-row chunk
    const int scol = ((lane & 3) ^ ((lane >> 3) & 3)) * 8;    // swizzled k-halves

    floatx4 acc[4][4] = {};

    auto stA = [&](int reg, int kcol) {  // 8 KB region: 2 glls/thread
        _Float16* dst = SA + reg * G1_REG + wave * 1024;
        gll16(gA + (long)(wave * 32 + srow) * K1 + kcol + scol, dst);
        gll16(gA + (long)(wave * 32 + 16 + srow) * K1 + kcol + scol, dst + 512);
    };
    auto stB = [&](int reg, int kcol) {
        _Float16* dst = SB + reg * G1_REG + wave * 1024;
        gll16(gB + (long)(wave * 32 + srow) * K1 + kcol + scol, dst);
        gll16(gB + (long)(wave * 32 + 16 + srow) * K1 + kcol + scol, dst + 512);
    };
    auto ldA = [&](int reg, int i) -> half8 {
        return *(const half8*)&SA[reg * G1_REG + (wm * 64 + i * 16 + lm) * 32 + soff];
    };
    auto ldB = [&](int reg, int j) -> half8 {
        return *(const half8*)&SB[reg * G1_REG + (wn_ * 64 + j * 16 + lm) * 32 + soff];
    };

    // prologue: [0][0]<-t0ks0, [0][1]<-t0ks1, [1][0]<-t1ks0  (12 glls/thread)
    stA(0, 0);  stB(0, 0);
    stA(1, 32); stB(1, 32);
    stA(2, 64); stB(2, 64);
    asm volatile("s_waitcnt vmcnt(8)" ::: "memory");  // oldest batch (t0ks0) landed
    __builtin_amdgcn_s_barrier();
    __builtin_amdgcn_sched_barrier(0);

    for (int k = 0; k < 18; ++k) {
        const int b = k & 1;
        const int rg0 = b * 2, rg1 = rg0 + 1, og1 = (b ^ 1) * 2 + 1;
        // ---------- phase q0: compute ks0 ----------
        {
            half8 af[4], bf[4];
#pragma unroll
            for (int i = 0; i < 4; ++i) af[i] = ldA(rg0, i);
#pragma unroll
            for (int j = 0; j < 4; ++j) bf[j] = ldB(rg0, j);
            if (k + 1 < 18) {
                int kc = (k + 1) * 64 + 32;
                stA(og1, kc); stB(og1, kc);
                asm volatile("s_waitcnt vmcnt(8) lgkmcnt(0)" ::: "memory");
            } else {
                asm volatile("s_waitcnt vmcnt(0) lgkmcnt(0)" ::: "memory");
            }
            __builtin_amdgcn_s_barrier();
            __builtin_amdgcn_sched_barrier(0);
            __builtin_amdgcn_s_setprio(1);
#pragma unroll
            for (int i = 0; i < 4; ++i)
#pragma unroll
                for (int j = 0; j < 4; ++j)
                    acc[i][j] = __builtin_amdgcn_mfma_f32_16x16x32_f16(af[i], bf[j], acc[i][j], 0, 0, 0);
            __builtin_amdgcn_s_setprio(0);
        }
        // ---------- phase q1: compute ks1 ----------
        {
            half8 af[4], bf[4];
#pragma unroll
            for (int i = 0; i < 4; ++i) af[i] = ldA(rg1, i);
#pragma unroll
            for (int j = 0; j < 4; ++j) bf[j] = ldB(rg1, j);
            if (k + 2 < 18) {
                int kc = (k + 2) * 64;
                stA(rg0, kc); stB(rg0, kc);
                asm volatile("s_waitcnt vmcnt(8) lgkmcnt(0)" ::: "memory");
            } else {
                asm volatile("s_waitcnt vmcnt(0) lgkmcnt(0)" ::: "memory");
            }
            __builtin_amdgcn_s_barrier();
            __builtin_amdgcn_sched_barrier(0);
            __builtin_amdgcn_s_setprio(1);
#pragma unroll
            for (int i = 0; i < 4; ++i)
#pragma unroll
                for (int j = 0; j < 4; ++j)
                    acc[i][j] = __builtin_amdgcn_mfma_f32_16x16x32_f16(af[i], bf[j], acc[i][j], 0, 0, 0);
            __builtin_amdgcn_s_setprio(0);
        }
    }

    // C/D layout: col = lane&15, row = (lane>>4)*4 + reg   [m89-verified]
    const int col = n0 + wn_ * 64 + lm;
#pragma unroll
    for (int i = 0; i < 4; ++i) {
        const int row = m0 + wm * 64 + i * 16 + q * 4;
#pragma unroll
        for (int j = 0; j < 4; ++j)
#pragma unroll
            for (int r = 0; r < 4; ++r)
                Cb[(long)(row + r) * LBF + col + j * 16] = acc[i][j][r];
    }
}

// ---------------- NT GEMM, BK=64, double-buffered LDS (R6 winner) — GEMM2 -----
__device__ __forceinline__ void gemm_compute(const _Float16* lA, const _Float16* lB,
                                             floatx4 (&acc)[4][4],
                                             int wr, int wc, int lm, int pcp) {
    half8 af[4], bf[4];
#pragma unroll
    for (int t = 0; t < 4; t++) {
        af[t] = *(const half8*)&lA[(wr * 64 + t * 16 + lm) * 64 + pcp];
        bf[t] = *(const half8*)&lB[(wc * 64 + t * 16 + lm) * 64 + pcp];
    }
#pragma unroll
    for (int i = 0; i < 4; i++)
#pragma unroll
        for (int j = 0; j < 4; j++)
            acc[i][j] = __builtin_amdgcn_mfma_f32_16x16x32_f16(af[i], bf[j], acc[i][j], 0, 0, 0);
#pragma unroll
    for (int t = 0; t < 4; t++) {
        af[t] = *(const half8*)&lA[(wr * 64 + t * 16 + lm) * 64 + (pcp ^ 32)];
        bf[t] = *(const half8*)&lB[(wc * 64 + t * 16 + lm) * 64 + (pcp ^ 32)];
    }
#pragma unroll
    for (int i = 0; i < 4; i++)
#pragma unroll
        for (int j = 0; j < 4; j++)
            acc[i][j] = __builtin_amdgcn_mfma_f32_16x16x32_f16(af[i], bf[j], acc[i][j], 0, 0, 0);
}

__global__ __launch_bounds__(256)
void gemm_nt64(const _Float16* __restrict__ A, const _Float16* __restrict__ B,
               float* __restrict__ C, int M, int N, int ldk, int swapxy,
               const int* __restrict__ Kpos, int Kstat, long sA, long sB, long sC) {
    A += blockIdx.z * sA; B += blockIdx.z * sB; C += blockIdx.z * sC;
    int K;
    if (Kpos) { int kc = dec_kc(Kpos[0]); K = (kc + 63) & ~63; }
    else K = Kstat;
    const int tid = threadIdx.x;
    const int lane = tid & 63, wave = tid >> 6;
    const int wr = wave >> 1, wc = wave & 1;
    const int bm = swapxy ? blockIdx.x : blockIdx.y;
    const int bn = swapxy ? blockIdx.y : blockIdx.x;
    const int m0 = bm * 128, n0 = bn * 128;

    __shared__ _Float16 sm[4][128 * 64];   // [buf*2 + (A=0/B=1)]: 4 x 16 KB

    floatx4 acc[4][4] = {};

    const int lm = lane & 15, q = lane >> 4;
    const int pcp = (q ^ (lm & 7)) * 8;      // substep-0 phys offset (halves)

    const int srow8 = lane >> 3;
    const int gc = ((lane & 7) ^ srow8) * 8;  // global halves offset (XOR swizzle)
    const _Float16* gA[4]; const _Float16* gB[4];
    int dOff[4];
#pragma unroll
    for (int c = 0; c < 4; c++) {
        int r = (wave * 4 + c) * 8 + srow8;
        gA[c] = A + (long)(m0 + r) * ldk + gc;
        gB[c] = B + (long)(n0 + r) * ldk + gc;
        dOff[c] = (wave * 4 + c) * 512;
    }

    if (K > 0) {
#pragma unroll
        for (int c = 0; c < 4; c++) gll16(gA[c], &sm[0][dOff[c]]);
#pragma unroll
        for (int c = 0; c < 4; c++) gll16(gB[c], &sm[1][dOff[c]]);
        __syncthreads();
        int k0 = 0, buf = 0;
        while (true) {
            int kn = k0 + 64;
            if (kn < K) {
                const int nb = (buf ^ 1) * 2;
#pragma unroll
                for (int c = 0; c < 4; c++) gll16(gA[c] + kn, &sm[nb][dOff[c]]);
#pragma unroll
                for (int c = 0; c < 4; c++) gll16(gB[c] + kn, &sm[nb + 1][dOff[c]]);
            }
            gemm_compute(sm[buf * 2], sm[buf * 2 + 1], acc, wr, wc, lm, pcp);
            __syncthreads();
            k0 = kn; buf ^= 1;
            if (k0 >= K) break;
        }
    }

    // C/D layout: col = lane&15, row = (lane>>4)*4 + reg   [m89-verified]
    const int col = n0 + wc * 64 + lm;
    const int rowq = q * 4;
#pragma unroll
    for (int i = 0; i < 4; i++) {
        int row = m0 + wr * 64 + i * 16 + rowq;
#pragma unroll
        for (int j = 0; j < 4; j++)
#pragma unroll
            for (int r = 0; r < 4; r++)
                C[(long)(row + r) * N + col + j * 16] = acc[i][j][r];
    }
}

// ---------------- fuse pass A: FT1[y][x] = sum_d ST[y+d][x+d], float4 ---------
__global__ __launch_bounds__(256)
void fuseA(const float* __restrict__ ST, float* __restrict__ FT1) {
    int y = blockIdx.x, bb = blockIdx.y;
    const float* S = ST + (long)bb * LBF * LBF;
    float* F = FT1 + (long)bb * LBF * LBF;
    const float* r0 = S + (long)(y > 0 ? y - 1 : 0) * LBF;
    const float* r1 = S + (long)y * LBF;
    const float* r2 = S + (long)(y < LBF - 1 ? y + 1 : y) * LBF;
    float m0 = (y > 0) ? 1.f : 0.f;
    float m2 = (y < LBF - 1) ? 1.f : 0.f;
    float* o = F + (long)y * LBF;
    int tid = threadIdx.x;
#pragma unroll
    for (int u = 0; u < 3; u++) {
        int qq = tid + u * 256;              // float4 index [0, 576)
        if (qq < LBF / 4) {
            int x0 = qq * 4;
            float4 a = *(const float4*)(r1 + x0);
            float4 b = *(const float4*)(r0 + x0);
            float4 c = *(const float4*)(r2 + x0);
            float lo_m1 = (x0 > 0) ? r0[x0 - 1] : 0.f;
            float hi_p4 = (x0 + 4 < LBF) ? r2[x0 + 4] : 0.f;
            float4 out;
            out.x = a.x + m0 * lo_m1 + m2 * c.y;
            out.y = a.y + m0 * b.x + m2 * c.z;
            out.z = a.z + m0 * b.y + m2 * c.w;
            out.w = a.w + m0 * b.z + m2 * hi_p4;
            *(float4*)(o + x0) = out;
        }
    }
}

// ---------------- fuse pass B + masked softmax + compaction + self-pad --------
__global__ __launch_bounds__(256)
void fuseB_softmax(const float* __restrict__ FT1, const int* __restrict__ pos,
                   _Float16* __restrict__ attTc_g) {
    int j = blockIdx.x, bb = blockIdx.y;
    int tid = threadIdx.x;
    const float* F = FT1 + (long)bb * LBF * LBF;
    _Float16* orow = attTc_g + ((long)bb * LBF + j) * LDK2;
    int Pj = (j % 48) * 48 + j / 48;
    long roff[3]; bool jok[3];
#pragma unroll
    for (int t = 0; t < 3; t++) {
        int j2 = Pj + t - 1;
        jok[t] = (unsigned)j2 < (unsigned)LBF;
        int jc = jok[t] ? j2 : 0;
        roff[t] = (long)((jc % 48) * 48 + jc / 48) * LBF;
    }
    float v[9]; int ps[9];
    float mx = -1e30f;
#pragma unroll
    for (int u = 0; u < 9; u++) {
        int x = tid + u * 256;
        int sp = pos[x];
        ps[u] = sp;
        float xv = 0.f;
        if (sp >= 0) {
            int a = x / 48, b = x - a * 48;
            int Px = b * 48 + a;
            float acc = 0.f;
#pragma unroll
            for (int t = 0; t < 3; t++) {
                int d2 = t - 1;
                int uu = Px + d2;
                if (jok[t] && (unsigned)uu < (unsigned)LBF) {
                    int ad = a + d2;
                    int c = ((unsigned)ad < 48u) ? (x + 48 * d2)
                          : (ad == 48 ? (b + 1) : (2255 + b));
                    acc += F[roff[t] + c];
                }
            }
            xv = acc * 10.f;
        }
        v[u] = xv;
        mx = fmaxf(mx, xv);
    }
    for (int m = 32; m; m >>= 1) mx = fmaxf(mx, __shfl_xor(mx, m));
    __shared__ float sh[4], sh2[4];
    if ((tid & 63) == 0) sh[tid >> 6] = mx;
    __syncthreads();
    mx = fmaxf(fmaxf(sh[0], sh[1]), fmaxf(sh[2], sh[3]));
    float sum = 0.f;
#pragma unroll
    for (int u = 0; u < 9; u++) { v[u] = __expf(v[u] - mx); sum += v[u]; }
    for (int m = 32; m; m >>= 1) sum += __shfl_xor(sum, m);
    if ((tid & 63) == 0) sh2[tid >> 6] = sum;
    __syncthreads();
    sum = sh2[0] + sh2[1] + sh2[2] + sh2[3];
    float inv = 1.f / sum;
#pragma unroll
    for (int u = 0; u < 9; u++) {
        if (ps[u] >= 0) orow[ps[u]] = (_Float16)(v[u] * inv);
    }
    int kc = dec_kc(pos[2303]);
    int kp = (kc + 63) & ~63;
    if (tid < kp - kc) orow[kc + tid] = (_Float16)0.f;
}

// ---------------- scatter from MT[n][p]: coalesced transposed-conv gather -----
__global__ void scatter_out(const float* __restrict__ MT_, float* __restrict__ out) {
    int yx = blockIdx.x * 256 + threadIdx.x;  // [0, 9216)
    int c = blockIdx.y, b = blockIdx.z;
    int y = yx / 96, x = yx % 96;
    const float* Mb = MT_ + (long)b * 2048 * LBF;
    float s = 0.f;
    for (int uu = (y + 1) & 1; uu < 4; uu += 2) {
        int fi = (y + 1 - uu) >> 1;
        if ((unsigned)fi >= 48u) continue;
        for (int vv = (x + 1) & 1; vv < 4; vv += 2) {
            int fj = (x + 1 - vv) >> 1;
            if ((unsigned)fj >= 48u) continue;
            s += Mb[(long)(c * 16 + uu * 4 + vv) * LBF + fi * 48 + fj];
        }
    }
    out[(((long)b * 128 + c) * 96 + y) * 96 + x] = 0.25f * s;
}

extern "C" void kernel_launch(void* const* d_in, const int* in_sizes, int n_in,
                              void* d_out, int out_size, void* d_ws, size_t ws_size,
                              hipStream_t stream) {
    const float* f    = (const float*)d_in[0];
    const float* bsrc = (const float*)d_in[1];
    const float* mask = (const float*)d_in[2];
    float* out = (float*)d_out;

    char* ws = (char*)d_ws;
    const size_t offR1  = 84934656;
    const size_t offWn  = offR1 + 21233664;
    const size_t offWtc = offR1 + 42467328;
    const size_t offFT1 = offWtc + 37748736;          // 165150720
    const size_t offPos = offFT1 + 2ul * 21233664;    // 207618048
    const size_t NEED   = offPos + 9216;              // 207627264
    if (ws_size < NEED) return;  // visible failure, no OOB writes

    float*    ST    = (float*)(ws + 0);
    float*    MT    = (float*)(ws + 0);
    _Float16* fp    = (_Float16*)(ws + offR1);
    _Float16* wn    = (_Float16*)(ws + offWn);
    _Float16* attTc = (_Float16*)(ws + offR1);
    _Float16* Wtc   = (_Float16*)(ws + offWtc);
    float*    FT1   = (float*)(ws + offFT1);   // 2-batch FT1 slot
    int*      pos   = (int*)(ws + offPos);

    mask_scan<<<dim3(1), 256, 0, stream>>>(mask, pos);
    prep_fp2<<<dim3(48, 4, 4), 256, 0, stream>>>(f, fp);
    prep_wn<<<dim3(2304, 4), 256, 0, stream>>>(bsrc, wn);
    prep_wtc<<<dim3(9, 128, 4), 256, 0, stream>>>(bsrc, pos, Wtc);

    // GEMM1: ST[j,i] = sum_k fp[j,k] * wn[i,k]  (static K=1152)
    gemm1_cv<<<dim3(1296), 256, 0, stream>>>(fp, wn, ST);

    // proven fuse split: streaming fuseA (float4) + fuseB softmax
    for (int g = 0; g < 2; g++) {
        fuseA<<<dim3(LBF, 2), 256, 0, stream>>>(ST + (long)g * 2 * LBF * LBF, FT1);
        fuseB_softmax<<<dim3(LBF, 2), 256, 0, stream>>>(FT1, pos,
            attTc + (long)g * 2 * LBF * LDK2);
    }

    // GEMM2 transposed output, R4 block-order: x sweeps Wtc (A), y pins attTc (B)
    gemm_nt64<<<dim3(16, 18, 4), 256, 0, stream>>>(Wtc, attTc, MT, 2048, 2304, LDK2, 1,
        pos + 2303, 0, (long)2048 * LDK2, (long)2304 * LDK2, (long)2048 * 2304);

    scatter_out<<<dim3(36, 128, 4), 256, 0, stream>>>(MT, out);
}